// Round 12
// baseline (3157.618 us; speedup 1.0000x reference)
//
#include <hip/hip_runtime.h>

#define HID    2048
#define G3     6144   // 3*HID
#define NVOCAB 128
#define SEQ    512
#define NBLK   256
#define TAGBASE 0x5EED0000u

__device__ __forceinline__ float sigmoidf_(float x) {
  return 1.f / (1.f + __expf(-x));
}
__device__ __forceinline__ float tanhf_(float x) {
  const float ax = fabsf(x);
  const float e2 = __expf(-2.f * ax);
  return copysignf((1.f - e2) / (1.f + e2), x);
}

// ---------------------------------------------------------------------------
// Kernel 1: GI[v][j] = dot(w_ih[j,:], emb[v,:]) + b_ih[j]
// ---------------------------------------------------------------------------
__global__ __launch_bounds__(256) void gi_precompute(
    const float* __restrict__ emb,
    const float* __restrict__ w_ih,
    const float* __restrict__ b_ih,
    float* __restrict__ GI) {
  __shared__ float sE[64][33];
  __shared__ float sW[64][33];

  const int j0 = blockIdx.x * 64;
  const int v0 = blockIdx.y * 64;
  const int tid = threadIdx.x;
  const int tx = tid & 15;
  const int ty = tid >> 4;
  const int r  = tid >> 3;
  const int c4 = (tid & 7) * 4;

  float acc[4][4] = {};

  for (int k0 = 0; k0 < HID; k0 += 32) {
    __syncthreads();
    float4 eA = *(const float4*)&emb [(size_t)(v0 + r)      * HID + k0 + c4];
    float4 eB = *(const float4*)&emb [(size_t)(v0 + r + 32) * HID + k0 + c4];
    float4 wA = *(const float4*)&w_ih[(size_t)(j0 + r)      * HID + k0 + c4];
    float4 wB = *(const float4*)&w_ih[(size_t)(j0 + r + 32) * HID + k0 + c4];
    sE[r][c4+0] = eA.x; sE[r][c4+1] = eA.y; sE[r][c4+2] = eA.z; sE[r][c4+3] = eA.w;
    sE[r+32][c4+0] = eB.x; sE[r+32][c4+1] = eB.y; sE[r+32][c4+2] = eB.z; sE[r+32][c4+3] = eB.w;
    sW[r][c4+0] = wA.x; sW[r][c4+1] = wA.y; sW[r][c4+2] = wA.z; sW[r][c4+3] = wA.w;
    sW[r+32][c4+0] = wB.x; sW[r+32][c4+1] = wB.y; sW[r+32][c4+2] = wB.z; sW[r+32][c4+3] = wB.w;
    __syncthreads();

    #pragma unroll
    for (int kk = 0; kk < 32; ++kk) {
      float e0 = sE[ty*4+0][kk], e1 = sE[ty*4+1][kk];
      float e2 = sE[ty*4+2][kk], e3 = sE[ty*4+3][kk];
      float w0 = sW[tx*4+0][kk], w1 = sW[tx*4+1][kk];
      float w2 = sW[tx*4+2][kk], w3 = sW[tx*4+3][kk];
      acc[0][0] += e0*w0; acc[0][1] += e0*w1; acc[0][2] += e0*w2; acc[0][3] += e0*w3;
      acc[1][0] += e1*w0; acc[1][1] += e1*w1; acc[1][2] += e1*w2; acc[1][3] += e1*w3;
      acc[2][0] += e2*w0; acc[2][1] += e2*w1; acc[2][2] += e2*w2; acc[2][3] += e2*w3;
      acc[3][0] += e3*w0; acc[3][1] += e3*w1; acc[3][2] += e3*w2; acc[3][3] += e3*w3;
    }
  }

  #pragma unroll
  for (int a = 0; a < 4; ++a)
    #pragma unroll
    for (int b = 0; b < 4; ++b) {
      const int j = j0 + tx*4 + b;
      GI[(size_t)(v0 + ty*4 + a) * G3 + j] = acc[a][b] + b_ih[j];
    }
}

// ---------------------------------------------------------------------------
// Persistent GRU — r11 core (192 AGPR-pinned weights, tagged 8B exchange,
// setprio) + barrier-free chunk-pipelined consume:
//   * s_h double-buffered in LDS (no end-of-step barrier; cross-block data
//     dependence proves s_h[p] is fully read before any s+2 staging).
//   * per-chunk monotone LDS counters (release add on stage, acquire spin
//     before chunk FMA) -> FMA of early chunks overlaps arrival of late ones.
// ---------------------------------------------------------------------------
__global__ __launch_bounds__(256, 1) void gru_reg(
    const float* __restrict__ GI,
    const float* __restrict__ Whh,
    const float* __restrict__ bhh,
    const int*   __restrict__ inputs,
    const float* __restrict__ wout,
    const float* __restrict__ bout,
    unsigned long long* __restrict__ D,   // [2][2048] tagged pairs (32 KB)
    float* __restrict__ out,
    const float* __restrict__ hx) {

  __shared__ int      s_inp[SEQ];
  __shared__ float    s_h[2][HID];       // double buffer by step parity
  __shared__ unsigned s_cnt[2][32];      // counter j at [p][j*4] (bank-spread)
  __shared__ float    s_logits[2];

  const int tid  = threadIdx.x;
  const int lane = tid & 63;
  const int wv   = tid >> 6;
  const int i0 = blockIdx.x * 4 + wv;   // 0..1023
  const int i1 = i0 + 1024;             // 1024..2047

  for (int k = tid; k < SEQ; k += 256) s_inp[k] = inputs[k];
  if (tid < 64) ((unsigned*)s_cnt)[tid] = 0;

  // ---- preload 6 W_hh rows (192 regs/lane), pin into AGPRs ----
  float w_r0[32], w_z0[32], w_n0[32], w_r1[32], w_z1[32], w_n1[32];
  {
    const float* pr0 = Whh + (size_t)i0 * HID;
    const float* pz0 = Whh + (size_t)(i0 + HID) * HID;
    const float* pn0 = Whh + (size_t)(i0 + 2*HID) * HID;
    const float* pr1 = Whh + (size_t)i1 * HID;
    const float* pz1 = Whh + (size_t)(i1 + HID) * HID;
    const float* pn1 = Whh + (size_t)(i1 + 2*HID) * HID;
    #pragma unroll
    for (int c = 0; c < 8; ++c) {
      const int k = c * 256 + lane * 4;
      *(float4*)&w_r0[c*4] = *(const float4*)&pr0[k];
      *(float4*)&w_z0[c*4] = *(const float4*)&pz0[k];
      *(float4*)&w_n0[c*4] = *(const float4*)&pn0[k];
      *(float4*)&w_r1[c*4] = *(const float4*)&pr1[k];
      *(float4*)&w_z1[c*4] = *(const float4*)&pz1[k];
      *(float4*)&w_n1[c*4] = *(const float4*)&pn1[k];
    }
  }
  #pragma unroll
  for (int c = 0; c < 32; ++c) {
    asm volatile("" : "+a"(w_r0[c]), "+a"(w_z0[c]), "+a"(w_n0[c]),
                      "+a"(w_r1[c]), "+a"(w_z1[c]), "+a"(w_n1[c]));
  }

  const float br0 = bhh[i0], bz0 = bhh[i0+HID], bn0 = bhh[i0+2*HID];
  const float br1 = bhh[i1], bz1 = bhh[i1+HID], bn1 = bhh[i1+2*HID];

  __syncthreads();   // s_inp + counters ready

  float g0r, g0z, g0n, g1r, g1z, g1n;
  {
    const float* gp = GI + (size_t)s_inp[0] * G3;
    g0r = gp[i0]; g0z = gp[i0+HID]; g0n = gp[i0+2*HID];
    g1r = gp[i1]; g1z = gp[i1+HID]; g1n = gp[i1+2*HID];
  }

  for (int s = 0; s < SEQ; ++s) {
    const int p = s & 1;

    // ---- stage h (version s) into s_h[p], counting per-chunk arrivals ----
    if (s == 0) {
      #pragma unroll
      for (int j = 0; j < 8; ++j) s_h[0][j*256 + tid] = hx[j*256 + tid];
      __syncthreads();
    } else {
      const unsigned want = TAGBASE | (unsigned)s;
      const unsigned long long* br_ = D + (size_t)p * HID;
      unsigned pending = 0xFFu;
      bool first = true;
      while (pending) {
        if (!first) __builtin_amdgcn_s_sleep(1);
        first = false;
        unsigned long long x[8];
        #pragma unroll
        for (int j = 0; j < 8; ++j)
          if (pending & (1u << j))
            x[j] = __hip_atomic_load(br_ + j*256 + tid, __ATOMIC_RELAXED,
                                     __HIP_MEMORY_SCOPE_AGENT);
        #pragma unroll
        for (int j = 0; j < 8; ++j)
          if ((pending & (1u << j)) && (unsigned)(x[j] >> 32) == want) {
            s_h[p][j*256 + tid] = __uint_as_float((unsigned)x[j]);
            __hip_atomic_fetch_add(&s_cnt[p][j*4], 1u, __ATOMIC_RELEASE,
                                   __HIP_MEMORY_SCOPE_WORKGROUP);
            pending &= ~(1u << j);
          }
      }
    }

    // ---- prefetch next step's GI scalars (independent of h) ----
    float ng0r=g0r, ng0z=g0z, ng0n=g0n, ng1r=g1r, ng1z=g1z, ng1n=g1n;
    if (s + 1 < SEQ) {
      const float* gp = GI + (size_t)s_inp[s+1] * G3;
      ng0r = gp[i0]; ng0z = gp[i0+HID]; ng0n = gp[i0+2*HID];
      ng1r = gp[i1]; ng1z = gp[i1+HID]; ng1n = gp[i1+2*HID];
    }

    // ---- chunk-pipelined FMA: spin (LDS, block-local) then consume ----
    __builtin_amdgcn_s_setprio(1);
    const unsigned target = 256u * (unsigned)((s + 1) >> 1);
    float ar0=0.f, az0=0.f, an0=0.f, ar1=0.f, az1=0.f, an1=0.f;
    #pragma unroll
    for (int c = 0; c < 8; ++c) {
      if (s) {
        while (__hip_atomic_load(&s_cnt[p][c*4], __ATOMIC_ACQUIRE,
                                 __HIP_MEMORY_SCOPE_WORKGROUP) < target) { }
      }
      const float4 h4 = *(const float4*)&s_h[p][c*256 + lane*4];
      ar0 = fmaf(w_r0[c*4+0], h4.x, ar0); ar0 = fmaf(w_r0[c*4+1], h4.y, ar0);
      ar0 = fmaf(w_r0[c*4+2], h4.z, ar0); ar0 = fmaf(w_r0[c*4+3], h4.w, ar0);
      az0 = fmaf(w_z0[c*4+0], h4.x, az0); az0 = fmaf(w_z0[c*4+1], h4.y, az0);
      az0 = fmaf(w_z0[c*4+2], h4.z, az0); az0 = fmaf(w_z0[c*4+3], h4.w, az0);
      an0 = fmaf(w_n0[c*4+0], h4.x, an0); an0 = fmaf(w_n0[c*4+1], h4.y, an0);
      an0 = fmaf(w_n0[c*4+2], h4.z, an0); an0 = fmaf(w_n0[c*4+3], h4.w, an0);
      ar1 = fmaf(w_r1[c*4+0], h4.x, ar1); ar1 = fmaf(w_r1[c*4+1], h4.y, ar1);
      ar1 = fmaf(w_r1[c*4+2], h4.z, ar1); ar1 = fmaf(w_r1[c*4+3], h4.w, ar1);
      az1 = fmaf(w_z1[c*4+0], h4.x, az1); az1 = fmaf(w_z1[c*4+1], h4.y, az1);
      az1 = fmaf(w_z1[c*4+2], h4.z, az1); az1 = fmaf(w_z1[c*4+3], h4.w, az1);
      an1 = fmaf(w_n1[c*4+0], h4.x, an1); an1 = fmaf(w_n1[c*4+1], h4.y, an1);
      an1 = fmaf(w_n1[c*4+2], h4.z, an1); an1 = fmaf(w_n1[c*4+3], h4.w, an1);
    }

    const float hp0 = s_h[p][i0], hp1 = s_h[p][i1];

    #pragma unroll
    for (int m = 32; m > 0; m >>= 1) {
      ar0 += __shfl_xor(ar0, m); az0 += __shfl_xor(az0, m); an0 += __shfl_xor(an0, m);
      ar1 += __shfl_xor(ar1, m); az1 += __shfl_xor(az1, m); an1 += __shfl_xor(an1, m);
    }

    // ---- gates + immediate per-wave publish (earliest visibility) ----
    if (lane == 0) {
      const unsigned tagv = TAGBASE | (unsigned)(s + 1);
      unsigned long long* bw = D + (size_t)((s + 1) & 1) * HID;
      const float r0 = sigmoidf_(g0r + ar0 + br0);
      const float z0 = sigmoidf_(g0z + az0 + bz0);
      const float n0 = tanhf_(g0n + r0 * (an0 + bn0));
      const float h0n = (1.f - z0) * n0 + z0 * hp0;
      const float r1 = sigmoidf_(g1r + ar1 + br1);
      const float z1 = sigmoidf_(g1z + az1 + bz1);
      const float n1 = tanhf_(g1n + r1 * (an1 + bn1));
      const float h1n = (1.f - z1) * n1 + z1 * hp1;
      __hip_atomic_store(bw + i0,
          ((unsigned long long)tagv << 32) | (unsigned long long)__float_as_uint(h0n),
          __ATOMIC_RELAXED, __HIP_MEMORY_SCOPE_AGENT);
      __hip_atomic_store(bw + i1,
          ((unsigned long long)tagv << 32) | (unsigned long long)__float_as_uint(h1n),
          __ATOMIC_RELAXED, __HIP_MEMORY_SCOPE_AGENT);
    }
    __builtin_amdgcn_s_setprio(0);

    g0r = ng0r; g0z = ng0z; g0n = ng0n;
    g1r = ng1r; g1z = ng1z; g1n = ng1n;
    // NO end-of-step barrier: s_h is parity double-buffered; staging of
    // version s+2 is transitively gated on this block's s+1 publish, which
    // follows every wave's step-s reads in program order.
  }

  // ======================= epilogue (block 0 only) =======================
  if (blockIdx.x == 0) {
    // stage version SEQ (parity 0)
    {
      const unsigned want = TAGBASE | (unsigned)SEQ;
      const unsigned long long* br_ = D;   // SEQ&1 == 0
      unsigned pending = 0xFFu;
      while (pending) {
        unsigned long long x[8];
        #pragma unroll
        for (int j = 0; j < 8; ++j)
          if (pending & (1u << j))
            x[j] = __hip_atomic_load(br_ + j*256 + tid, __ATOMIC_RELAXED,
                                     __HIP_MEMORY_SCOPE_AGENT);
        #pragma unroll
        for (int j = 0; j < 8; ++j)
          if ((pending & (1u << j)) && (unsigned)(x[j] >> 32) == want) {
            s_h[0][j*256 + tid] = __uint_as_float((unsigned)x[j]);
            pending &= ~(1u << j);
          }
      }
    }
    __syncthreads();

    if (wv < 2) {
      const float* wo = wout + (size_t)wv * HID;
      float acc = 0.f;
      #pragma unroll
      for (int c = 0; c < 8; ++c) {
        const float4 h4 = *(const float4*)&s_h[0][c*256 + lane*4];
        const float4 a4 = *(const float4*)&wo[c*256 + lane*4];
        acc += a4.x*h4.x + a4.y*h4.y + a4.z*h4.z + a4.w*h4.w;
      }
      #pragma unroll
      for (int m = 32; m > 0; m >>= 1) acc += __shfl_xor(acc, m);
      if (lane == 0) s_logits[wv] = acc + bout[wv];
    }
    __syncthreads();
    if (tid == 0) {
      const float l0 = s_logits[0], l1 = s_logits[1];
      const float mx = fmaxf(l0, l1);
      const float lse = mx + logf(expf(l0 - mx) + expf(l1 - mx));
      out[0] = l0 - lse;
      out[1] = l1 - lse;
    }
  }
}

// ---------------------------------------------------------------------------
// Fallback (non-cooperative) path: one kernel per timestep.
// ---------------------------------------------------------------------------
__global__ __launch_bounds__(256) void gru_step_fb(
    const float* __restrict__ GI,
    const float* __restrict__ Whh,
    const float* __restrict__ bhh,
    const int*   __restrict__ inputs, int t,
    const float* __restrict__ h_in,
    float* __restrict__ h_out) {
  const int lane = threadIdx.x & 63;
  const int wvv  = threadIdx.x >> 6;
  const int i = blockIdx.x * 4 + wvv;
  const int v = inputs[t];

  const float4* hv = (const float4*)h_in;
  const float4* wr = (const float4*)(Whh + (size_t)i*HID);
  const float4* wz = (const float4*)(Whh + (size_t)(i+HID)*HID);
  const float4* wn = (const float4*)(Whh + (size_t)(i+2*HID)*HID);

  float ar=0.f, az=0.f, an=0.f;
  #pragma unroll
  for (int c = 0; c < 8; ++c) {
    const int idx = c*64 + lane;
    const float4 h4 = hv[idx];
    float4 a;
    a = wr[idx]; ar += a.x*h4.x + a.y*h4.y + a.z*h4.z + a.w*h4.w;
    a = wz[idx]; az += a.x*h4.x + a.y*h4.y + a.z*h4.z + a.w*h4.w;
    a = wn[idx]; an += a.x*h4.x + a.y*h4.y + a.z*h4.z + a.w*h4.w;
  }
  #pragma unroll
  for (int m = 32; m > 0; m >>= 1) {
    ar += __shfl_xor(ar, m); az += __shfl_xor(az, m); an += __shfl_xor(an, m);
  }
  if (lane == 0) {
    const float* gi = GI + (size_t)v * G3;
    const float r = sigmoidf_(gi[i] + ar + bhh[i]);
    const float z = sigmoidf_(gi[i+HID] + az + bhh[i+HID]);
    const float n = tanhf_(gi[i+2*HID] + r * (an + bhh[i+2*HID]));
    h_out[i] = (1.f - z) * n + z * h_in[i];
  }
}

__global__ void gru_out_fb(const float* __restrict__ h,
                           const float* __restrict__ wout,
                           const float* __restrict__ bout,
                           float* out) {
  __shared__ float logits[2];
  const int lane = threadIdx.x & 63;
  const int wvv  = threadIdx.x >> 6;
  if (wvv < 2) {
    const float4* wo = (const float4*)(wout + (size_t)wvv * HID);
    const float4* hv = (const float4*)h;
    float acc = 0.f;
    #pragma unroll
    for (int c = 0; c < 8; ++c) {
      const int idx = c*64 + lane;
      const float4 a  = wo[idx];
      const float4 h4 = hv[idx];
      acc += a.x*h4.x + a.y*h4.y + a.z*h4.z + a.w*h4.w;
    }
    #pragma unroll
    for (int m = 32; m > 0; m >>= 1) acc += __shfl_xor(acc, m);
    if (lane == 0) logits[wvv] = acc + bout[wvv];
  }
  __syncthreads();
  if (threadIdx.x == 0) {
    const float l0 = logits[0], l1 = logits[1];
    const float mx = fmaxf(l0, l1);
    const float lse = mx + logf(expf(l0 - mx) + expf(l1 - mx));
    out[0] = l0 - lse;
    out[1] = l1 - lse;
  }
}

// ---------------------------------------------------------------------------
extern "C" void kernel_launch(void* const* d_in, const int* in_sizes, int n_in,
                              void* d_out, int out_size, void* d_ws, size_t ws_size,
                              hipStream_t stream) {
  const int*   inputs = (const int*)  d_in[0];
  const float* hx     = (const float*)d_in[1];
  const float* emb    = (const float*)d_in[2];
  const float* w_ih   = (const float*)d_in[3];
  const float* w_hh   = (const float*)d_in[4];
  const float* b_ih   = (const float*)d_in[5];
  const float* b_hh   = (const float*)d_in[6];
  const float* w_out  = (const float*)d_in[7];
  const float* b_out  = (const float*)d_in[8];
  float* out = (float*)d_out;

  float* GI = (float*)d_ws;                                        // 3.0 MB
  unsigned long long* D =
      (unsigned long long*)((char*)d_ws + (size_t)NVOCAB * G3 * 4); // 32 KB

  // Clean exchange region each launch (stale-tag/garbage immunity).
  hipMemsetAsync(D, 0, 2 * HID * 8, stream);

  gi_precompute<<<dim3(G3/64, NVOCAB/64), 256, 0, stream>>>(emb, w_ih, b_ih, GI);

  void* args[] = { (void*)&GI, (void*)&w_hh, (void*)&b_hh, (void*)&inputs,
                   (void*)&w_out, (void*)&b_out, (void*)&D,
                   (void*)&out, (void*)&hx };
  hipError_t ce = hipLaunchCooperativeKernel((void*)gru_reg, dim3(NBLK), dim3(256),
                                             args, 0, stream);
  if (ce != hipSuccess) {
    float* h0 = (float*)D;             // fallback reuses exchange region
    float* h1 = h0 + HID;
    const float* hin = hx;
    for (int t = 0; t < SEQ; ++t) {
      float* hout = (t & 1) ? h1 : h0;
      gru_step_fb<<<512, 256, 0, stream>>>(GI, w_hh, b_hh, inputs, t, hin, hout);
      hin = hout;
    }
    gru_out_fb<<<1, 128, 0, stream>>>(hin, w_out, b_out, out);
  }
}

// Round 13
// 2065.706 us; speedup vs baseline: 1.5286x; 1.5286x over previous
//
#include <hip/hip_runtime.h>

#define HID    2048
#define G3     6144   // 3*HID
#define NVOCAB 128
#define SEQ    512
#define NBLK   256
#define TAGBASE 0x5EED0000u

__device__ __forceinline__ float sigmoidf_(float x) {
  return 1.f / (1.f + __expf(-x));
}
__device__ __forceinline__ float tanhf_(float x) {
  const float ax = fabsf(x);
  const float e2 = __expf(-2.f * ax);
  return copysignf((1.f - e2) / (1.f + e2), x);
}

// ---------------------------------------------------------------------------
// Kernel 1: GI[v][j] = dot(w_ih[j,:], emb[v,:]) + b_ih[j]
// ---------------------------------------------------------------------------
__global__ __launch_bounds__(256) void gi_precompute(
    const float* __restrict__ emb,
    const float* __restrict__ w_ih,
    const float* __restrict__ b_ih,
    float* __restrict__ GI) {
  __shared__ float sE[64][33];
  __shared__ float sW[64][33];

  const int j0 = blockIdx.x * 64;
  const int v0 = blockIdx.y * 64;
  const int tid = threadIdx.x;
  const int tx = tid & 15;
  const int ty = tid >> 4;
  const int r  = tid >> 3;
  const int c4 = (tid & 7) * 4;

  float acc[4][4] = {};

  for (int k0 = 0; k0 < HID; k0 += 32) {
    __syncthreads();
    float4 eA = *(const float4*)&emb [(size_t)(v0 + r)      * HID + k0 + c4];
    float4 eB = *(const float4*)&emb [(size_t)(v0 + r + 32) * HID + k0 + c4];
    float4 wA = *(const float4*)&w_ih[(size_t)(j0 + r)      * HID + k0 + c4];
    float4 wB = *(const float4*)&w_ih[(size_t)(j0 + r + 32) * HID + k0 + c4];
    sE[r][c4+0] = eA.x; sE[r][c4+1] = eA.y; sE[r][c4+2] = eA.z; sE[r][c4+3] = eA.w;
    sE[r+32][c4+0] = eB.x; sE[r+32][c4+1] = eB.y; sE[r+32][c4+2] = eB.z; sE[r+32][c4+3] = eB.w;
    sW[r][c4+0] = wA.x; sW[r][c4+1] = wA.y; sW[r][c4+2] = wA.z; sW[r][c4+3] = wA.w;
    sW[r+32][c4+0] = wB.x; sW[r+32][c4+1] = wB.y; sW[r+32][c4+2] = wB.z; sW[r+32][c4+3] = wB.w;
    __syncthreads();

    #pragma unroll
    for (int kk = 0; kk < 32; ++kk) {
      float e0 = sE[ty*4+0][kk], e1 = sE[ty*4+1][kk];
      float e2 = sE[ty*4+2][kk], e3 = sE[ty*4+3][kk];
      float w0 = sW[tx*4+0][kk], w1 = sW[tx*4+1][kk];
      float w2 = sW[tx*4+2][kk], w3 = sW[tx*4+3][kk];
      acc[0][0] += e0*w0; acc[0][1] += e0*w1; acc[0][2] += e0*w2; acc[0][3] += e0*w3;
      acc[1][0] += e1*w0; acc[1][1] += e1*w1; acc[1][2] += e1*w2; acc[1][3] += e1*w3;
      acc[2][0] += e2*w0; acc[2][1] += e2*w1; acc[2][2] += e2*w2; acc[2][3] += e2*w3;
      acc[3][0] += e3*w0; acc[3][1] += e3*w1; acc[3][2] += e3*w2; acc[3][3] += e3*w3;
    }
  }

  #pragma unroll
  for (int a = 0; a < 4; ++a)
    #pragma unroll
    for (int b = 0; b < 4; ++b) {
      const int j = j0 + tx*4 + b;
      GI[(size_t)(v0 + ty*4 + a) * G3 + j] = acc[a][b] + b_ih[j];
    }
}

// ---------------------------------------------------------------------------
// Persistent GRU — r11 configuration (measured best: 2069 us total).
// 192 AGPR-pinned weight regs; tagged 8B-pair exchange, per-wave immediate
// publish; per-thread row poll with s_sleep backoff; s_setprio around the
// compute phase; per-step __syncthreads keeps the grid phase-aligned
// (r12 showed removing it doubles poll traffic and costs +50%).
// ---------------------------------------------------------------------------
__global__ __launch_bounds__(256, 1) void gru_reg(
    const float* __restrict__ GI,
    const float* __restrict__ Whh,
    const float* __restrict__ bhh,
    const int*   __restrict__ inputs,
    const float* __restrict__ wout,
    const float* __restrict__ bout,
    unsigned long long* __restrict__ D,   // [2][2048] tagged pairs (32 KB)
    float* __restrict__ out,
    const float* __restrict__ hx) {

  __shared__ int   s_inp[SEQ];
  __shared__ float s_h[HID];
  __shared__ float s_logits[2];

  const int tid  = threadIdx.x;
  const int lane = tid & 63;
  const int wv   = tid >> 6;
  const int i0 = blockIdx.x * 4 + wv;   // 0..1023
  const int i1 = i0 + 1024;             // 1024..2047

  for (int k = tid; k < SEQ; k += 256) s_inp[k] = inputs[k];

  // ---- preload 6 W_hh rows (192 regs/lane), pin into AGPRs ----
  float w_r0[32], w_z0[32], w_n0[32], w_r1[32], w_z1[32], w_n1[32];
  {
    const float* pr0 = Whh + (size_t)i0 * HID;
    const float* pz0 = Whh + (size_t)(i0 + HID) * HID;
    const float* pn0 = Whh + (size_t)(i0 + 2*HID) * HID;
    const float* pr1 = Whh + (size_t)i1 * HID;
    const float* pz1 = Whh + (size_t)(i1 + HID) * HID;
    const float* pn1 = Whh + (size_t)(i1 + 2*HID) * HID;
    #pragma unroll
    for (int c = 0; c < 8; ++c) {
      const int k = c * 256 + lane * 4;
      *(float4*)&w_r0[c*4] = *(const float4*)&pr0[k];
      *(float4*)&w_z0[c*4] = *(const float4*)&pz0[k];
      *(float4*)&w_n0[c*4] = *(const float4*)&pn0[k];
      *(float4*)&w_r1[c*4] = *(const float4*)&pr1[k];
      *(float4*)&w_z1[c*4] = *(const float4*)&pz1[k];
      *(float4*)&w_n1[c*4] = *(const float4*)&pn1[k];
    }
  }
  #pragma unroll
  for (int c = 0; c < 32; ++c) {
    asm volatile("" : "+a"(w_r0[c]), "+a"(w_z0[c]), "+a"(w_n0[c]),
                      "+a"(w_r1[c]), "+a"(w_z1[c]), "+a"(w_n1[c]));
  }

  const float br0 = bhh[i0], bz0 = bhh[i0+HID], bn0 = bhh[i0+2*HID];
  const float br1 = bhh[i1], bz1 = bhh[i1+HID], bn1 = bhh[i1+2*HID];

  __syncthreads();   // s_inp ready

  float g0r, g0z, g0n, g1r, g1z, g1n;
  {
    const float* gp = GI + (size_t)s_inp[0] * G3;
    g0r = gp[i0]; g0z = gp[i0+HID]; g0n = gp[i0+2*HID];
    g1r = gp[i1]; g1z = gp[i1+HID]; g1n = gp[i1+2*HID];
  }

  for (int s = 0; s < SEQ; ++s) {
    // ---- stage h (version s) into LDS ----
    if (s == 0) {
      #pragma unroll
      for (int j = 0; j < 8; ++j) s_h[j*256 + tid] = hx[j*256 + tid];
    } else {
      const unsigned want = TAGBASE | (unsigned)s;
      const unsigned long long* br_ = D + (size_t)(s & 1) * HID;
      unsigned pending = 0xFFu;
      bool first = true;
      while (pending) {
        if (!first) __builtin_amdgcn_s_sleep(1);
        first = false;
        unsigned long long x[8];
        #pragma unroll
        for (int j = 0; j < 8; ++j)
          if (pending & (1u << j))
            x[j] = __hip_atomic_load(br_ + j*256 + tid, __ATOMIC_RELAXED,
                                     __HIP_MEMORY_SCOPE_AGENT);
        #pragma unroll
        for (int j = 0; j < 8; ++j)
          if ((pending & (1u << j)) && (unsigned)(x[j] >> 32) == want) {
            s_h[j*256 + tid] = __uint_as_float((unsigned)x[j]);
            pending &= ~(1u << j);
          }
      }
    }
    __syncthreads();

    // ---- prefetch next step's GI scalars (independent of h) ----
    float ng0r=g0r, ng0z=g0z, ng0n=g0n, ng1r=g1r, ng1z=g1z, ng1n=g1n;
    if (s + 1 < SEQ) {
      const float* gp = GI + (size_t)s_inp[s+1] * G3;
      ng0r = gp[i0]; ng0z = gp[i0+HID]; ng0n = gp[i0+2*HID];
      ng1r = gp[i1]; ng1z = gp[i1+HID]; ng1n = gp[i1+2*HID];
    }

    // ---- 6 dot products: LDS h x AGPR weights (priority-boosted) ----
    __builtin_amdgcn_s_setprio(1);
    float ar0=0.f, az0=0.f, an0=0.f, ar1=0.f, az1=0.f, an1=0.f;
    #pragma unroll
    for (int c = 0; c < 8; ++c) {
      const float4 h4 = *(const float4*)&s_h[c*256 + lane*4];
      ar0 = fmaf(w_r0[c*4+0], h4.x, ar0); ar0 = fmaf(w_r0[c*4+1], h4.y, ar0);
      ar0 = fmaf(w_r0[c*4+2], h4.z, ar0); ar0 = fmaf(w_r0[c*4+3], h4.w, ar0);
      az0 = fmaf(w_z0[c*4+0], h4.x, az0); az0 = fmaf(w_z0[c*4+1], h4.y, az0);
      az0 = fmaf(w_z0[c*4+2], h4.z, az0); az0 = fmaf(w_z0[c*4+3], h4.w, az0);
      an0 = fmaf(w_n0[c*4+0], h4.x, an0); an0 = fmaf(w_n0[c*4+1], h4.y, an0);
      an0 = fmaf(w_n0[c*4+2], h4.z, an0); an0 = fmaf(w_n0[c*4+3], h4.w, an0);
      ar1 = fmaf(w_r1[c*4+0], h4.x, ar1); ar1 = fmaf(w_r1[c*4+1], h4.y, ar1);
      ar1 = fmaf(w_r1[c*4+2], h4.z, ar1); ar1 = fmaf(w_r1[c*4+3], h4.w, ar1);
      az1 = fmaf(w_z1[c*4+0], h4.x, az1); az1 = fmaf(w_z1[c*4+1], h4.y, az1);
      az1 = fmaf(w_z1[c*4+2], h4.z, az1); az1 = fmaf(w_z1[c*4+3], h4.w, az1);
      an1 = fmaf(w_n1[c*4+0], h4.x, an1); an1 = fmaf(w_n1[c*4+1], h4.y, an1);
      an1 = fmaf(w_n1[c*4+2], h4.z, an1); an1 = fmaf(w_n1[c*4+3], h4.w, an1);
    }

    const float hp0 = s_h[i0], hp1 = s_h[i1];

    #pragma unroll
    for (int m = 32; m > 0; m >>= 1) {
      ar0 += __shfl_xor(ar0, m); az0 += __shfl_xor(az0, m); an0 += __shfl_xor(an0, m);
      ar1 += __shfl_xor(ar1, m); az1 += __shfl_xor(az1, m); an1 += __shfl_xor(an1, m);
    }

    // ---- gates + immediate per-wave publish (earliest visibility) ----
    if (lane == 0) {
      const unsigned tagv = TAGBASE | (unsigned)(s + 1);
      unsigned long long* bw = D + (size_t)((s + 1) & 1) * HID;
      const float r0 = sigmoidf_(g0r + ar0 + br0);
      const float z0 = sigmoidf_(g0z + az0 + bz0);
      const float n0 = tanhf_(g0n + r0 * (an0 + bn0));
      const float h0n = (1.f - z0) * n0 + z0 * hp0;
      const float r1 = sigmoidf_(g1r + ar1 + br1);
      const float z1 = sigmoidf_(g1z + az1 + bz1);
      const float n1 = tanhf_(g1n + r1 * (an1 + bn1));
      const float h1n = (1.f - z1) * n1 + z1 * hp1;
      __hip_atomic_store(bw + i0,
          ((unsigned long long)tagv << 32) | (unsigned long long)__float_as_uint(h0n),
          __ATOMIC_RELAXED, __HIP_MEMORY_SCOPE_AGENT);
      __hip_atomic_store(bw + i1,
          ((unsigned long long)tagv << 32) | (unsigned long long)__float_as_uint(h1n),
          __ATOMIC_RELAXED, __HIP_MEMORY_SCOPE_AGENT);
    }
    __builtin_amdgcn_s_setprio(0);

    g0r = ng0r; g0z = ng0z; g0n = ng0n;
    g1r = ng1r; g1z = ng1z; g1n = ng1n;

    __syncthreads();   // protect s_h before next stage-in overwrites it
  }

  // ======================= epilogue (block 0 only) =======================
  if (blockIdx.x == 0) {
    // stage version SEQ (parity 0)
    {
      const unsigned want = TAGBASE | (unsigned)SEQ;
      const unsigned long long* br_ = D;   // SEQ&1 == 0
      unsigned pending = 0xFFu;
      while (pending) {
        unsigned long long x[8];
        #pragma unroll
        for (int j = 0; j < 8; ++j)
          if (pending & (1u << j))
            x[j] = __hip_atomic_load(br_ + j*256 + tid, __ATOMIC_RELAXED,
                                     __HIP_MEMORY_SCOPE_AGENT);
        #pragma unroll
        for (int j = 0; j < 8; ++j)
          if ((pending & (1u << j)) && (unsigned)(x[j] >> 32) == want) {
            s_h[j*256 + tid] = __uint_as_float((unsigned)x[j]);
            pending &= ~(1u << j);
          }
      }
    }
    __syncthreads();

    if (wv < 2) {
      const float* wo = wout + (size_t)wv * HID;
      float acc = 0.f;
      #pragma unroll
      for (int c = 0; c < 8; ++c) {
        const float4 h4 = *(const float4*)&s_h[c*256 + lane*4];
        const float4 a4 = *(const float4*)&wo[c*256 + lane*4];
        acc += a4.x*h4.x + a4.y*h4.y + a4.z*h4.z + a4.w*h4.w;
      }
      #pragma unroll
      for (int m = 32; m > 0; m >>= 1) acc += __shfl_xor(acc, m);
      if (lane == 0) s_logits[wv] = acc + bout[wv];
    }
    __syncthreads();
    if (tid == 0) {
      const float l0 = s_logits[0], l1 = s_logits[1];
      const float mx = fmaxf(l0, l1);
      const float lse = mx + logf(expf(l0 - mx) + expf(l1 - mx));
      out[0] = l0 - lse;
      out[1] = l1 - lse;
    }
  }
}

// ---------------------------------------------------------------------------
// Fallback (non-cooperative) path: one kernel per timestep.
// ---------------------------------------------------------------------------
__global__ __launch_bounds__(256) void gru_step_fb(
    const float* __restrict__ GI,
    const float* __restrict__ Whh,
    const float* __restrict__ bhh,
    const int*   __restrict__ inputs, int t,
    const float* __restrict__ h_in,
    float* __restrict__ h_out) {
  const int lane = threadIdx.x & 63;
  const int wvv  = threadIdx.x >> 6;
  const int i = blockIdx.x * 4 + wvv;
  const int v = inputs[t];

  const float4* hv = (const float4*)h_in;
  const float4* wr = (const float4*)(Whh + (size_t)i*HID);
  const float4* wz = (const float4*)(Whh + (size_t)(i+HID)*HID);
  const float4* wn = (const float4*)(Whh + (size_t)(i+2*HID)*HID);

  float ar=0.f, az=0.f, an=0.f;
  #pragma unroll
  for (int c = 0; c < 8; ++c) {
    const int idx = c*64 + lane;
    const float4 h4 = hv[idx];
    float4 a;
    a = wr[idx]; ar += a.x*h4.x + a.y*h4.y + a.z*h4.z + a.w*h4.w;
    a = wz[idx]; az += a.x*h4.x + a.y*h4.y + a.z*h4.z + a.w*h4.w;
    a = wn[idx]; an += a.x*h4.x + a.y*h4.y + a.z*h4.z + a.w*h4.w;
  }
  #pragma unroll
  for (int m = 32; m > 0; m >>= 1) {
    ar += __shfl_xor(ar, m); az += __shfl_xor(az, m); an += __shfl_xor(an, m);
  }
  if (lane == 0) {
    const float* gi = GI + (size_t)v * G3;
    const float r = sigmoidf_(gi[i] + ar + bhh[i]);
    const float z = sigmoidf_(gi[i+HID] + az + bhh[i+HID]);
    const float n = tanhf_(gi[i+2*HID] + r * (an + bhh[i+2*HID]));
    h_out[i] = (1.f - z) * n + z * h_in[i];
  }
}

__global__ void gru_out_fb(const float* __restrict__ h,
                           const float* __restrict__ wout,
                           const float* __restrict__ bout,
                           float* out) {
  __shared__ float logits[2];
  const int lane = threadIdx.x & 63;
  const int wvv  = threadIdx.x >> 6;
  if (wvv < 2) {
    const float4* wo = (const float4*)(wout + (size_t)wvv * HID);
    const float4* hv = (const float4*)h;
    float acc = 0.f;
    #pragma unroll
    for (int c = 0; c < 8; ++c) {
      const int idx = c*64 + lane;
      const float4 a  = wo[idx];
      const float4 h4 = hv[idx];
      acc += a.x*h4.x + a.y*h4.y + a.z*h4.z + a.w*h4.w;
    }
    #pragma unroll
    for (int m = 32; m > 0; m >>= 1) acc += __shfl_xor(acc, m);
    if (lane == 0) logits[wvv] = acc + bout[wvv];
  }
  __syncthreads();
  if (threadIdx.x == 0) {
    const float l0 = logits[0], l1 = logits[1];
    const float mx = fmaxf(l0, l1);
    const float lse = mx + logf(expf(l0 - mx) + expf(l1 - mx));
    out[0] = l0 - lse;
    out[1] = l1 - lse;
  }
}

// ---------------------------------------------------------------------------
extern "C" void kernel_launch(void* const* d_in, const int* in_sizes, int n_in,
                              void* d_out, int out_size, void* d_ws, size_t ws_size,
                              hipStream_t stream) {
  const int*   inputs = (const int*)  d_in[0];
  const float* hx     = (const float*)d_in[1];
  const float* emb    = (const float*)d_in[2];
  const float* w_ih   = (const float*)d_in[3];
  const float* w_hh   = (const float*)d_in[4];
  const float* b_ih   = (const float*)d_in[5];
  const float* b_hh   = (const float*)d_in[6];
  const float* w_out  = (const float*)d_in[7];
  const float* b_out  = (const float*)d_in[8];
  float* out = (float*)d_out;

  float* GI = (float*)d_ws;                                        // 3.0 MB
  unsigned long long* D =
      (unsigned long long*)((char*)d_ws + (size_t)NVOCAB * G3 * 4); // 32 KB

  // Clean exchange region each launch (stale-tag/garbage immunity; r7/r10
  // showed hipMemsetAsync is graph-capture-safe).
  hipMemsetAsync(D, 0, 2 * HID * 8, stream);

  gi_precompute<<<dim3(G3/64, NVOCAB/64), 256, 0, stream>>>(emb, w_ih, b_ih, GI);

  void* args[] = { (void*)&GI, (void*)&w_hh, (void*)&b_hh, (void*)&inputs,
                   (void*)&w_out, (void*)&b_out, (void*)&D,
                   (void*)&out, (void*)&hx };
  hipError_t ce = hipLaunchCooperativeKernel((void*)gru_reg, dim3(NBLK), dim3(256),
                                             args, 0, stream);
  if (ce != hipSuccess) {
    float* h0 = (float*)D;             // fallback reuses exchange region
    float* h1 = h0 + HID;
    const float* hin = hx;
    for (int t = 0; t < SEQ; ++t) {
      float* hout = (t & 1) ? h1 : h0;
      gru_step_fb<<<512, 256, 0, stream>>>(GI, w_hh, b_hh, inputs, t, hin, hout);
      hin = hout;
    }
    gru_out_fb<<<1, 128, 0, stream>>>(hin, w_out, b_out, out);
  }
}